// Round 12
// baseline (423.556 us; speedup 1.0000x reference)
//
#include <hip/hip_runtime.h>
#include <math.h>

// Problem constants (BaseSpectrogram1D)
#define L_LEN    131072
#define M_FRAMES 511
#define N_FFT    512
#define KH       257
#define FSTRIDE  256
#define B_BATCH  128

#define TM       16                 // frames per block
#define RSTRIDE  18                 // floats per LDS row (72 B: 8B-aligned, 4-way write conflict only)
#define OS_OFF   (256 * RSTRIDE)    // float offset Es -> Os (18432 B, fits 16-bit ds offset)
#define SQRT_N   22.62741699796952f // sqrt(512)

typedef float pkf2 __attribute__((ext_vector_type(2)));

__device__ __forceinline__ pkf2 pk_fma(pkf2 a, pkf2 b, pkf2 c) {
    pkf2 d; asm("v_pk_fma_f32 %0, %1, %2, %3" : "=v"(d) : "v"(a), "v"(b), "v"(c)); return d;
}
__device__ __forceinline__ pkf2 pk_mul(pkf2 a, pkf2 b) {
    pkf2 d; asm("v_pk_mul_f32 %0, %1, %2" : "=v"(d) : "v"(a), "v"(b)); return d;
}
// v_sin/cos_f32 take REVOLUTIONS; p=(n*k)&511 exact -> rev exact fp32
__device__ __forceinline__ float hw_sin_rev(float rev){float r;asm("v_sin_f32 %0, %1":"=v"(r):"v"(rev));return r;}
__device__ __forceinline__ float hw_cos_rev(float rev){float r;asm("v_cos_f32 %0, %1":"=v"(r):"v"(rev));return r;}

// ---------------------------------------------------------------------------
// Kernel 1: partial row sums, 8 chunks/row (1024 blocks); folded in spec_kernel.
// ---------------------------------------------------------------------------
__global__ __launch_bounds__(256) void pmean_kernel(const float* __restrict__ x,
                                                    float* __restrict__ partial) {
    const int b = blockIdx.x >> 3, chunk = blockIdx.x & 7;
    const float4* p = (const float4*)(x + (size_t)b * L_LEN + (size_t)chunk * (L_LEN / 8));
    float s = 0.f;
    const int nvec = L_LEN / 8 / 4;  // 4096
    for (int i = threadIdx.x; i < nvec; i += 256) {
        float4 v = p[i];
        s += (v.x + v.y) + (v.z + v.w);
    }
    for (int off = 32; off; off >>= 1) s += __shfl_down(s, off, 64);
    __shared__ float ws[4];
    if ((threadIdx.x & 63) == 0) ws[threadIdx.x >> 6] = s;
    __syncthreads();
    if (threadIdx.x == 0) partial[blockIdx.x] = (ws[0] + ws[1]) + (ws[2] + ws[3]);
}

// ---------------------------------------------------------------------------
// One n-step: 4 broadcast ds_read_b64 (compile-time row offset -> immediate),
// 16 acc pk-FMA + 16 rotation pk-ops across 4 bins.
// ---------------------------------------------------------------------------
__device__ __forceinline__ void nstep(const float* row,
                                      pkf2 re2[4][2], pkf2 im2[4][2],
                                      pkf2 c2[4], pkf2 s2[4],
                                      const pkf2 ck2[4], const pkf2 sk2[4],
                                      const pkf2 msk2[4]) {
    pkf2 e0 = *(const pkf2*)(row);
    pkf2 e1 = *(const pkf2*)(row + 2);
    pkf2 o0 = *(const pkf2*)(row + OS_OFF);
    pkf2 o1 = *(const pkf2*)(row + OS_OFF + 2);
    #pragma unroll
    for (int u = 0; u < 4; ++u) {
        re2[u][0] = pk_fma(e0, c2[u], re2[u][0]);
        im2[u][0] = pk_fma(o0, s2[u], im2[u][0]);
        re2[u][1] = pk_fma(e1, c2[u], re2[u][1]);
        im2[u][1] = pk_fma(o1, s2[u], im2[u][1]);
        pkf2 ta = pk_mul(c2[u], ck2[u]);
        pkf2 tb = pk_mul(c2[u], sk2[u]);
        c2[u] = pk_fma(s2[u], msk2[u], ta);
        s2[u] = pk_fma(s2[u], ck2[u],  tb);
    }
}

// ---------------------------------------------------------------------------
// Kernel 2: Hermitian-paired windowed DFT magnitude.
//   E[n]=S*(f[n]+f[512-n]), O[n]=S*(f[n]-f[512-n]); E[0]=S*f[0], O[0]=S*f[256]
//   re[k]=E[0]+(-1)^k O[0]+sum E[n]cos(2pi nk/512); im[k]=sum O[n]sin(...)
//   k=256: |E[0]+O[0]+sum (-1)^n E[n]|
// Thread (kg=t&63, fg=t>>6): bins k=kg+64u (u<4) x frames fg*4..fg*4+3.
// TM=16 -> LDS 38.9 KB -> 4 blocks/CU (4 waves/SIMD).
// ---------------------------------------------------------------------------
__global__ __launch_bounds__(256, 4) void spec_kernel(const float* __restrict__ x,
                                                      const float* __restrict__ w,
                                                      const float* __restrict__ partial,
                                                      float* __restrict__ out) {
    __shared__ __align__(16) float lds[512 * RSTRIDE + 512];
    float* Es  = lds;                     // [256][RSTRIDE]
    float* Os  = lds + OS_OFF;            // [256][RSTRIDE]
    float* wl  = lds + 512 * RSTRIDE;     // [512] (staging only)
    float* nyq = wl;                      // aliased: used after staging is done

    const int b  = blockIdx.x;
    const int m0 = blockIdx.y * TM;
    const int t  = threadIdx.x;

    float msum = 0.f;
    #pragma unroll
    for (int i = 0; i < 8; ++i) msum += partial[(b << 3) + i];
    const float mean = msum * (1.0f / (float)L_LEN);

    wl[t]       = w[t];
    wl[t + 256] = w[t + 256];
    __syncthreads();

    // ---- staging: thread t = n ----
    {
        const int n = t;
        const float* xb = x + (size_t)b * L_LEN + (size_t)m0 * FSTRIDE;
        #pragma unroll
        for (int f = 0; f < TM; ++f) {
            float Ev = 0.f, Ov = 0.f;
            if (m0 + f < M_FRAMES) {
                const float* xf = xb + f * FSTRIDE;
                if (n == 0) {
                    Ev = SQRT_N * ((xf[0]   - mean) * wl[0]);
                    Ov = SQRT_N * ((xf[256] - mean) * wl[256]);
                } else {
                    float a = (xf[n]       - mean) * wl[n];
                    float c = (xf[512 - n] - mean) * wl[512 - n];
                    Ev = SQRT_N * (a + c);
                    Ov = SQRT_N * (a - c);
                }
            }
            Es[n * RSTRIDE + f] = Ev;
            Os[n * RSTRIDE + f] = Ov;
        }
    }
    __syncthreads();

    // ---- main: 4 bins x 4 frames (2 pkf2) per thread ----
    const int kg = t & 63;
    const int fg = t >> 6;
    const float* Er = Es + 4 * fg;

    pkf2 re2[4][2], im2[4][2];

    {   // n=0 init: re = E0 + (-1)^k O0
        const float sg = (kg & 1) ? -1.f : 1.f;
        pkf2 sg2 = {sg, sg};
        pkf2 e0 = *(const pkf2*)(Er);
        pkf2 e1 = *(const pkf2*)(Er + 2);
        pkf2 o0 = *(const pkf2*)(Er + OS_OFF);
        pkf2 o1 = *(const pkf2*)(Er + OS_OFF + 2);
        pkf2 r0 = pk_fma(sg2, o0, e0);
        pkf2 r1 = pk_fma(sg2, o1, e1);
        #pragma unroll
        for (int u = 0; u < 4; ++u) {
            re2[u][0] = r0; re2[u][1] = r1;
            im2[u][0] = (pkf2){0.f, 0.f}; im2[u][1] = (pkf2){0.f, 0.f};
        }
    }

    // per-bin rotation constants e^{2pi i k/512}
    pkf2 ck2[4], sk2[4], msk2[4];
    #pragma unroll
    for (int u = 0; u < 4; ++u) {
        float rev = (float)(kg + 64 * u) * (1.0f / 512.0f);
        float ck = hw_cos_rev(rev), sk = hw_sin_rev(rev);
        ck2[u]  = (pkf2){ck, ck};
        sk2[u]  = (pkf2){sk, sk};
        msk2[u] = (pkf2){-sk, -sk};
    }

    // 4 segments; exact trig re-sync at n0 in {1,64,128,192}
    #pragma unroll 1
    for (int seg = 0; seg < 4; ++seg) {
        const int n0 = seg ? seg * 64 : 1;
        pkf2 c2[4], s2[4];
        #pragma unroll
        for (int u = 0; u < 4; ++u) {
            int p = (n0 * (kg + 64 * u)) & 511;
            float rev = (float)p * (1.0f / 512.0f);
            float c = hw_cos_rev(rev), s = hw_sin_rev(rev);
            c2[u] = (pkf2){c, c};
            s2[u] = (pkf2){s, s};
        }
        const float* pn;
        int nch;
        if (seg == 0) {  // prologue n=1..3, chunks cover 4..63
            nstep(Er + 1 * RSTRIDE, re2, im2, c2, s2, ck2, sk2, msk2);
            nstep(Er + 2 * RSTRIDE, re2, im2, c2, s2, ck2, sk2, msk2);
            nstep(Er + 3 * RSTRIDE, re2, im2, c2, s2, ck2, sk2, msk2);
            pn = Er + 4 * RSTRIDE;
            nch = 15;
        } else {
            pn = Er + n0 * RSTRIDE;
            nch = 16;
        }
        #pragma unroll 1
        for (int ch = 0; ch < nch; ++ch) {
            nstep(pn + 0 * RSTRIDE, re2, im2, c2, s2, ck2, sk2, msk2);
            nstep(pn + 1 * RSTRIDE, re2, im2, c2, s2, ck2, sk2, msk2);
            nstep(pn + 2 * RSTRIDE, re2, im2, c2, s2, ck2, sk2, msk2);
            nstep(pn + 3 * RSTRIDE, re2, im2, c2, s2, ck2, sk2, msk2);
            pn += 4 * RSTRIDE;
        }
    }

    // ---- store bins 0..255 (lanes = consecutive k -> coalesced) ----
    #pragma unroll
    for (int u = 0; u < 4; ++u) {
        #pragma unroll
        for (int j = 0; j < 2; ++j) {
            const int f0 = fg * 4 + 2 * j;
            if (m0 + f0 < M_FRAMES) {
                float r = re2[u][j].x, ii = im2[u][j].x;
                out[((size_t)b * M_FRAMES + (m0 + f0)) * KH + kg + 64 * u] =
                    sqrtf(fmaf(r, r, ii * ii));
            }
            if (m0 + f0 + 1 < M_FRAMES) {
                float r = re2[u][j].y, ii = im2[u][j].y;
                out[((size_t)b * M_FRAMES + (m0 + f0 + 1)) * KH + kg + 64 * u] =
                    sqrtf(fmaf(r, r, ii * ii));
            }
        }
    }

    // ---- Nyquist k=256: |E0 + O0 + sum_{n>=1} (-1)^n E[n]| ----
    {
        const int g = t >> 4, f = t & 15;   // 16 groups x 16 frames
        float acc = 0.f;
        const int nlo = g * 16;
        #pragma unroll
        for (int n2 = 0; n2 < 16; n2 += 2) {
            acc += Es[(nlo + n2) * RSTRIDE + f] - Es[(nlo + n2 + 1) * RSTRIDE + f];
        }
        __syncthreads();                    // wl reads long done; safe to overwrite
        nyq[g * 16 + f] = acc;
    }
    __syncthreads();
    if (t < TM) {
        const int f = t;
        if (m0 + f < M_FRAMES) {
            float acc = Os[f];  // O[0]
            #pragma unroll
            for (int g = 0; g < 16; ++g) acc += nyq[g * 16 + f];
            out[((size_t)b * M_FRAMES + (m0 + f)) * KH + 256] = fabsf(acc);
        }
    }
}

// ---------------------------------------------------------------------------
extern "C" void kernel_launch(void* const* d_in, const int* in_sizes, int n_in,
                              void* d_out, int out_size, void* d_ws, size_t ws_size,
                              hipStream_t stream) {
    const float* x = (const float*)d_in[0];
    const float* w = (const float*)d_in[1];
    float* out     = (float*)d_out;
    float* partial = (float*)d_ws;  // 1024 floats

    pmean_kernel<<<dim3(B_BATCH * 8), dim3(256), 0, stream>>>(x, partial);

    const int mtiles = (M_FRAMES + TM - 1) / TM;  // 32
    spec_kernel<<<dim3(B_BATCH, mtiles), dim3(256), 0, stream>>>(x, w, partial, out);
}